// Round 7
// baseline (946.326 us; speedup 1.0000x reference)
//
#include <hip/hip_runtime.h>

// RNNLM: logits[T,B,V] = (scan_t sigmoid(h@H + emb[x]@I + b1)) @ U + b2 ; plus final h.
// V=32000 E=1024 Hd=1024 T=64 B=32.
// R7: FUSED mega-kernel = recurrence (blocks 0..63, R6-proven path, 258us)
//     + overlapped projection (blocks 64..511). Each proj block holds a
//     64-col U^T panel as 32 MFMA B-frags in VGPRs (128 VGPRs, loaded once),
//     waits for the recurrence's cnt flag per step, then computes the 32x64
//     logit tile for that t. 52 blocks carry a second streamed-B panel.
//     512 blocks @ __launch_bounds__(256,2) + 32KB LDS -> 2 blocks/CU
//     co-resident (no deadlock). Projection work (~1.5us/step) hides under
//     the recurrence's 4us/step sync latency -> the 175us gemm256 vanishes.

typedef _Float16 f16;
typedef f16 f16x4 __attribute__((ext_vector_type(4)));
typedef f16 f16x8 __attribute__((ext_vector_type(8)));
typedef float f32x4 __attribute__((ext_vector_type(4)));

static constexpr int Vv = 32000, Ee = 1024, Hd = 1024, Tt = 64, Bb = 32;
static constexpr int Mm = Tt * Bb; // 2048 rows (t*B+b)
static constexpr int NBR = 64;     // recurrence blocks
static constexpr int NBP = 448;    // projection blocks

// async global->LDS, 16B per lane; LDS dest = wave-uniform base + lane*16
#define GLOAD16(g, l)                                                          \
  __builtin_amdgcn_global_load_lds(                                            \
      (const __attribute__((address_space(1))) void*)(g),                      \
      (__attribute__((address_space(3))) void*)(l), 16, 0, 0)

// ---------------- prep kernels ----------------

__global__ void transpose_cvt(const float* __restrict__ in, f16* __restrict__ out,
                              int K, int N) {
  __shared__ float t[32][33];
  int n0 = blockIdx.x * 32, k0 = blockIdx.y * 32;
  int tx = threadIdx.x, ty = threadIdx.y; // (32,8)
#pragma unroll
  for (int i = 0; i < 32; i += 8)
    t[ty + i][tx] = in[(size_t)(k0 + ty + i) * N + n0 + tx];
  __syncthreads();
#pragma unroll
  for (int i = 0; i < 32; i += 8)
    out[(size_t)(n0 + ty + i) * K + k0 + tx] = (f16)t[tx][ty + i];
}

__global__ void gather_emb(const int* __restrict__ tok, const float* __restrict__ emb,
                           f16* __restrict__ xg) {
  int m = blockIdx.x;
  int b = m % Bb, t = m / Bb;
  int token = tok[b * Tt + t];
  const float* src = emb + (size_t)token * Ee;
  f16* dst = xg + (size_t)m * Ee;
  int e = threadIdx.x * 4;
  float4 v = *(const float4*)(src + e);
  f16x4 o = {(f16)v.x, (f16)v.y, (f16)v.z, (f16)v.w};
  *(f16x4*)(dst + e) = o;
}

__global__ void cvt_h0(const float* __restrict__ h0, f16* __restrict__ h0f) {
  int i = blockIdx.x * 256 + threadIdx.x;
  h0f[i] = (f16)h0[i];
}

// ---------------- small GEMM (xI): 128x128 tile, BK=64, proven R4 ----------------
__global__ __launch_bounds__(256) void gemm_f16(
    const f16* __restrict__ A, const f16* __restrict__ Bt,
    const float* __restrict__ bias, float* __restrict__ C, int M, int N, int K) {
  __shared__ __align__(16) f16 As[128 * 64];
  __shared__ __align__(16) f16 Bs[128 * 64];

  const int nwg = gridDim.x, bid = blockIdx.x;
  const int cpx = nwg >> 3;
  const int i = (bid & 7) * cpx + (bid >> 3);
  const int ntm = M >> 7;
  const int tm = i % ntm, tn = i / ntm;

  const int tid = threadIdx.x;
  const int lane = tid & 63, wid = tid >> 6;
  const int wm = wid >> 1, wn = wid & 1;

  const int srow = lane >> 3;
  const int sslot = (lane & 7) ^ srow;
  const f16* gA = A + (size_t)(tm * 128 + wid * 8 + srow) * K + sslot * 8;
  const f16* gB = Bt + (size_t)(tn * 128 + wid * 8 + srow) * K + sslot * 8;
  f16* lA = As + wid * 8 * 64;
  f16* lB = Bs + wid * 8 * 64;

  f32x4 acc[4][4] = {};
  const int r = lane & 15, kb = lane >> 4;

  for (int kc = 0; kc < K; kc += 64) {
    __syncthreads();
#pragma unroll
    for (int rr = 0; rr < 4; ++rr) {
      GLOAD16(gA + (size_t)rr * 32 * K + kc, lA + rr * 2048);
      GLOAD16(gB + (size_t)rr * 32 * K + kc, lB + rr * 2048);
    }
    __syncthreads();

#pragma unroll
    for (int kk = 0; kk < 2; ++kk) {
      f16x8 af[4], bf[4];
#pragma unroll
      for (int ii = 0; ii < 4; ++ii) {
        const int rowA = wm * 64 + ii * 16 + r;
        const int rowB = wn * 64 + ii * 16 + r;
        const int slot = ((kk * 4 + kb) ^ (r & 7)) * 8;
        af[ii] = *(const f16x8*)(As + rowA * 64 + slot);
        bf[ii] = *(const f16x8*)(Bs + rowB * 64 + slot);
      }
#pragma unroll
      for (int ii = 0; ii < 4; ++ii)
#pragma unroll
        for (int jj = 0; jj < 4; ++jj)
          acc[ii][jj] = __builtin_amdgcn_mfma_f32_16x16x32_f16(af[ii], bf[jj], acc[ii][jj], 0, 0, 0);
    }
  }

  const int col0 = tn * 128 + wn * 64, row0 = tm * 128 + wm * 64;
#pragma unroll
  for (int ii = 0; ii < 4; ++ii)
#pragma unroll
    for (int jj = 0; jj < 4; ++jj) {
      int c = col0 + jj * 16 + (lane & 15);
      int rbase = row0 + ii * 16 + (lane >> 4) * 4;
      float bv = bias ? bias[c] : 0.f;
#pragma unroll
      for (int rr = 0; rr < 4; ++rr)
        C[(size_t)(rbase + rr) * N + c] = acc[ii][jj][rr] + bv;
    }
}

// ---------------- fused mega-kernel: recurrence + overlapped projection ----------------
__global__ __launch_bounds__(256, 2) void mega(
    const f16* __restrict__ Ht,    // H^T f16 [col][k]
    const float* __restrict__ xI,  // [T*B][Hd], includes b1
    const f16* __restrict__ h0f,   // [B][Hd] f16
    f16* __restrict__ hs,          // [T*B][Hd] f16
    float* __restrict__ hN,        // [B][Hd] f32 (final state -> d_out tail)
    int* __restrict__ cnt,         // grid-barrier counter
    const f16* __restrict__ Ut,    // U^T f16 [V][Hd]
    const float* __restrict__ b2,  // [V]
    float* __restrict__ out) {     // logits [T*B][V]
  __shared__ float red[4][2048]; // rec uses [4][512] prefix; proj uses [4][2048]
  const int tid = threadIdx.x;
  const int lane = tid & 63, w = tid >> 6;
  const int r = lane & 15, kb = lane >> 4;

  if (blockIdx.x < NBR) {
    // ================= recurrence role (R6-proven, 4.03us/step) =================
    const int bn = blockIdx.x;
    const int colg = bn * 16 + r;

    f16x8 bH[8];
#pragma unroll
    for (int ks = 0; ks < 8; ++ks)
      bH[ks] = *(const f16x8*)(Ht + (size_t)colg * Hd + w * 256 + ks * 32 + kb * 8);

    const int eb = tid >> 3, ecp = tid & 7;

#pragma unroll 1
    for (int t = 0; t < Tt; ++t) {
      const f16* hp = t ? hs + (size_t)(t - 1) * Bb * Hd : h0f;
      const float2 xv = *(const float2*)(xI + (size_t)(t * Bb + eb) * Hd + bn * 16 + 2 * ecp);
      f32x4 acc[2] = {};
#pragma unroll
      for (int mt = 0; mt < 2; ++mt) {
        f16x8 af[8];
#pragma unroll
        for (int ks = 0; ks < 8; ++ks)
          af[ks] = *(const f16x8*)(hp + (size_t)(mt * 16 + r) * Hd + w * 256 + ks * 32 + kb * 8);
#pragma unroll
        for (int ks = 0; ks < 8; ++ks)
          acc[mt] = __builtin_amdgcn_mfma_f32_16x16x32_f16(af[ks], bH[ks], acc[mt], 0, 0, 0);
      }
#pragma unroll
      for (int mt = 0; mt < 2; ++mt)
#pragma unroll
        for (int q = 0; q < 4; ++q)
          red[w][mt * 256 + (kb * 4 + q) * 16 + r] = acc[mt][q];
      __syncthreads();

      {
        const float2 r0 = *(const float2*)&red[0][eb * 16 + 2 * ecp];
        const float2 r1 = *(const float2*)&red[1][eb * 16 + 2 * ecp];
        const float2 r2 = *(const float2*)&red[2][eb * 16 + 2 * ecp];
        const float2 r3 = *(const float2*)&red[3][eb * 16 + 2 * ecp];
        float v0 = r0.x + r1.x + r2.x + r3.x + xv.x;
        float v1 = r0.y + r1.y + r2.y + r3.y + xv.y;
        float s0 = 1.f / (1.f + __expf(-v0));
        float s1 = 1.f / (1.f + __expf(-v1));
        union { f16 h[2]; unsigned u; } pk;
        pk.h[0] = (f16)s0;
        pk.h[1] = (f16)s1;
        unsigned* dst = (unsigned*)(hs + (size_t)(t * Bb + eb) * Hd + bn * 16 + 2 * ecp);
        __hip_atomic_store(dst, pk.u, __ATOMIC_RELAXED, __HIP_MEMORY_SCOPE_AGENT);
        if (t == Tt - 1)
          *(float2*)(hN + (size_t)eb * Hd + bn * 16 + 2 * ecp) = make_float2(s0, s1);
      }

      __syncthreads(); // vmcnt(0) drained block-wide (incl. sc1 h stores)
      if (tid == 0)
        (void)__hip_atomic_fetch_add(cnt, 1, __ATOMIC_RELAXED, __HIP_MEMORY_SCOPE_AGENT);
      const int target = (t + 1) * NBR;
      while (__hip_atomic_load(cnt, __ATOMIC_RELAXED, __HIP_MEMORY_SCOPE_AGENT) < target)
        __builtin_amdgcn_s_sleep(1);
      asm volatile("" ::: "memory");
    }
  } else {
    // ================= projection role =================
    const int pb = blockIdx.x - NBR;     // 0..447
    const int wk = w * 256;              // this wave's K-slice
    const size_t c1 = (size_t)pb * 64;
    const bool has2 = (pb < (Vv / 64 - NBP)); // 52 blocks carry a 2nd panel
    const size_t c2 = (size_t)(NBP + pb) * 64;

    // one-time B-frags for panel 1: Breg[nt][ks] = Ut[c1+nt*16+r][wk+ks*32+kb*8..]
    f16x8 Breg[4][8];
#pragma unroll
    for (int nt = 0; nt < 4; ++nt)
#pragma unroll
      for (int ks = 0; ks < 8; ++ks)
        Breg[nt][ks] = *(const f16x8*)(Ut + (c1 + nt * 16 + r) * (size_t)Hd + wk + ks * 32 + kb * 8);

#define PROJ_PANEL(CBASE, USEREG)                                              \
  do {                                                                         \
    f32x4 pacc[2][4] = {};                                                     \
    _Pragma("unroll") for (int ks = 0; ks < 8; ++ks) {                         \
      f16x8 af0 = *(const f16x8*)(hs + (size_t)(t * Bb + r) * Hd + wk + ks * 32 + kb * 8); \
      f16x8 af1 = *(const f16x8*)(hs + (size_t)(t * Bb + 16 + r) * Hd + wk + ks * 32 + kb * 8); \
      _Pragma("unroll") for (int nt = 0; nt < 4; ++nt) {                       \
        f16x8 bf = (USEREG) ? Breg[nt][ks]                                     \
                            : *(const f16x8*)(Ut + ((CBASE) + nt * 16 + r) * (size_t)Hd + wk + ks * 32 + kb * 8); \
        pacc[0][nt] = __builtin_amdgcn_mfma_f32_16x16x32_f16(af0, bf, pacc[0][nt], 0, 0, 0); \
        pacc[1][nt] = __builtin_amdgcn_mfma_f32_16x16x32_f16(af1, bf, pacc[1][nt], 0, 0, 0); \
      }                                                                        \
    }                                                                          \
    _Pragma("unroll") for (int mt = 0; mt < 2; ++mt)                           \
    _Pragma("unroll") for (int nt = 0; nt < 4; ++nt)                           \
    _Pragma("unroll") for (int q = 0; q < 4; ++q)                              \
      red[w][(mt * 16 + kb * 4 + q) * 64 + nt * 16 + r] = pacc[mt][nt][q];     \
    __syncthreads();                                                           \
    {                                                                          \
      const int prow = tid >> 3, pc8 = (tid & 7) * 8;                          \
      float* orow = out + (size_t)(t * Bb + prow) * Vv + (CBASE) + pc8;        \
      _Pragma("unroll") for (int j = 0; j < 8; ++j)                            \
        orow[j] = red[0][prow * 64 + pc8 + j] + red[1][prow * 64 + pc8 + j] +  \
                  red[2][prow * 64 + pc8 + j] + red[3][prow * 64 + pc8 + j] +  \
                  b2[(CBASE) + pc8 + j];                                       \
    }                                                                          \
    __syncthreads();                                                           \
  } while (0)

#pragma unroll 1
    for (int t = 0; t < Tt; ++t) {
      // wait until recurrence published h_t (cnt reaches (t+1)*NBR)
      if (w == 0) {
        while (__hip_atomic_load(cnt, __ATOMIC_RELAXED, __HIP_MEMORY_SCOPE_AGENT) < (t + 1) * NBR)
          __builtin_amdgcn_s_sleep(32);
      }
      __syncthreads();
      asm volatile("" ::: "memory"); // no hs-load hoisting above the poll

      PROJ_PANEL(c1, true);
      if (has2) PROJ_PANEL(c2, false);
    }
#undef PROJ_PANEL
  }
}

// ---------------- launcher ----------------
extern "C" void kernel_launch(void* const* d_in, const int* in_sizes, int n_in,
                              void* d_out, int out_size, void* d_ws, size_t ws_size,
                              hipStream_t stream) {
  const int* input_x = (const int*)d_in[0];
  const float* h0 = (const float*)d_in[1];
  const float* emb = (const float*)d_in[2];
  const float* Hm = (const float*)d_in[3];
  const float* Im = (const float*)d_in[4];
  const float* b1 = (const float*)d_in[5];
  const float* Um = (const float*)d_in[6];
  const float* b2 = (const float*)d_in[7];
  float* out = (float*)d_out;

  char* ws = (char*)d_ws;
  size_t off = 0;
  auto alloc = [&](size_t bytes) { void* p = ws + off; off = (off + bytes + 255) & ~(size_t)255; return p; };
  f16* Ut = (f16*)alloc((size_t)Vv * Hd * 2);
  f16* It = (f16*)alloc((size_t)Hd * Ee * 2);
  f16* Ht = (f16*)alloc((size_t)Hd * Hd * 2);
  f16* xg = (f16*)alloc((size_t)Mm * Ee * 2);
  float* xI = (float*)alloc((size_t)Mm * Hd * 4);
  f16* hs = (f16*)alloc((size_t)Mm * Hd * 2);
  f16* h0f = (f16*)alloc((size_t)Bb * Hd * 2);
  int* cnt = (int*)alloc(256);
  (void)ws_size; (void)in_sizes; (void)n_in; (void)out_size;

  hipMemsetAsync(cnt, 0, sizeof(int), stream);

  transpose_cvt<<<dim3(Vv / 32, Hd / 32), dim3(32, 8), 0, stream>>>(Um, Ut, Hd, Vv);
  transpose_cvt<<<dim3(Hd / 32, Ee / 32), dim3(32, 8), 0, stream>>>(Im, It, Ee, Hd);
  transpose_cvt<<<dim3(Hd / 32, Hd / 32), dim3(32, 8), 0, stream>>>(Hm, Ht, Hd, Hd);
  gather_emb<<<Mm, 256, 0, stream>>>(input_x, emb, xg);
  cvt_h0<<<(Bb * Hd) / 256, 256, 0, stream>>>(h0, h0f);

  // xI = xg @ I + b1   (M=2048, N=1024, K=1024), grid 128 (%8==0)
  gemm_f16<<<(Mm / 128) * (Hd / 128), 256, 0, stream>>>(xg, It, b1, xI, Mm, Hd, Ee);

  // fused recurrence + overlapped projection -> hs, final h, logits
  mega<<<NBR + NBP, 256, 0, stream>>>(Ht, xI, h0f, hs, out + (size_t)Mm * Vv, cnt,
                                      Ut, b2, out);
}

// Round 8
// 520.522 us; speedup vs baseline: 1.8180x; 1.8180x over previous
//
#include <hip/hip_runtime.h>

// RNNLM: logits[T,B,V] = (scan_t sigmoid(h@H + emb[x]@I + b1)) @ U + b2 ; plus final h.
// V=32000 E=1024 Hd=1024 T=64 B=32.
// R8: REVERT R7 fusion (proj L3 traffic + flag-line hammering stretched the
// recurrence step 4->14.3us). Back to R6 split structure (494us proven), plus:
//  (1) recurrence: quarter-grained barrier. 4 arrival counters on separate
//      cache lines (parallel RMW streams, was 64 serialized RMWs on 1 line);
//      wave w polls only its K-quarter's counter (16 producers), so waves
//      unblock staggered instead of waiting for all 64 blocks.
//  (2) gemm256: nontemporal C stores (logits are write-once; keep Ut/hs in L2).

typedef _Float16 f16;
typedef f16 f16x4 __attribute__((ext_vector_type(4)));
typedef f16 f16x8 __attribute__((ext_vector_type(8)));
typedef float f32x4 __attribute__((ext_vector_type(4)));

static constexpr int Vv = 32000, Ee = 1024, Hd = 1024, Tt = 64, Bb = 32;
static constexpr int Mm = Tt * Bb; // 2048 rows (t*B+b)

// async global->LDS, 16B per lane; LDS dest = wave-uniform base + lane*16
#define GLOAD16(g, l)                                                          \
  __builtin_amdgcn_global_load_lds(                                            \
      (const __attribute__((address_space(1))) void*)(g),                      \
      (__attribute__((address_space(3))) void*)(l), 16, 0, 0)

// ---------------- prep kernels ----------------

__global__ void transpose_cvt(const float* __restrict__ in, f16* __restrict__ out,
                              int K, int N) {
  __shared__ float t[32][33];
  int n0 = blockIdx.x * 32, k0 = blockIdx.y * 32;
  int tx = threadIdx.x, ty = threadIdx.y; // (32,8)
#pragma unroll
  for (int i = 0; i < 32; i += 8)
    t[ty + i][tx] = in[(size_t)(k0 + ty + i) * N + n0 + tx];
  __syncthreads();
#pragma unroll
  for (int i = 0; i < 32; i += 8)
    out[(size_t)(n0 + ty + i) * K + k0 + tx] = (f16)t[tx][ty + i];
}

__global__ void gather_emb(const int* __restrict__ tok, const float* __restrict__ emb,
                           f16* __restrict__ xg) {
  int m = blockIdx.x;
  int b = m % Bb, t = m / Bb;
  int token = tok[b * Tt + t];
  const float* src = emb + (size_t)token * Ee;
  f16* dst = xg + (size_t)m * Ee;
  int e = threadIdx.x * 4;
  float4 v = *(const float4*)(src + e);
  f16x4 o = {(f16)v.x, (f16)v.y, (f16)v.z, (f16)v.w};
  *(f16x4*)(dst + e) = o;
}

__global__ void cvt_h0(const float* __restrict__ h0, f16* __restrict__ h0f) {
  int i = blockIdx.x * 256 + threadIdx.x;
  h0f[i] = (f16)h0[i];
}

// ---------------- small GEMM (xI): 128x128 tile, BK=64, proven R4 ----------------
__global__ __launch_bounds__(256) void gemm_f16(
    const f16* __restrict__ A, const f16* __restrict__ Bt,
    const float* __restrict__ bias, float* __restrict__ C, int M, int N, int K) {
  __shared__ __align__(16) f16 As[128 * 64];
  __shared__ __align__(16) f16 Bs[128 * 64];

  const int nwg = gridDim.x, bid = blockIdx.x;
  const int cpx = nwg >> 3;
  const int i = (bid & 7) * cpx + (bid >> 3);
  const int ntm = M >> 7;
  const int tm = i % ntm, tn = i / ntm;

  const int tid = threadIdx.x;
  const int lane = tid & 63, wid = tid >> 6;
  const int wm = wid >> 1, wn = wid & 1;

  const int srow = lane >> 3;
  const int sslot = (lane & 7) ^ srow;
  const f16* gA = A + (size_t)(tm * 128 + wid * 8 + srow) * K + sslot * 8;
  const f16* gB = Bt + (size_t)(tn * 128 + wid * 8 + srow) * K + sslot * 8;
  f16* lA = As + wid * 8 * 64;
  f16* lB = Bs + wid * 8 * 64;

  f32x4 acc[4][4] = {};
  const int r = lane & 15, kb = lane >> 4;

  for (int kc = 0; kc < K; kc += 64) {
    __syncthreads();
#pragma unroll
    for (int rr = 0; rr < 4; ++rr) {
      GLOAD16(gA + (size_t)rr * 32 * K + kc, lA + rr * 2048);
      GLOAD16(gB + (size_t)rr * 32 * K + kc, lB + rr * 2048);
    }
    __syncthreads();

#pragma unroll
    for (int kk = 0; kk < 2; ++kk) {
      f16x8 af[4], bf[4];
#pragma unroll
      for (int ii = 0; ii < 4; ++ii) {
        const int rowA = wm * 64 + ii * 16 + r;
        const int rowB = wn * 64 + ii * 16 + r;
        const int slot = ((kk * 4 + kb) ^ (r & 7)) * 8;
        af[ii] = *(const f16x8*)(As + rowA * 64 + slot);
        bf[ii] = *(const f16x8*)(Bs + rowB * 64 + slot);
      }
#pragma unroll
      for (int ii = 0; ii < 4; ++ii)
#pragma unroll
        for (int jj = 0; jj < 4; ++jj)
          acc[ii][jj] = __builtin_amdgcn_mfma_f32_16x16x32_f16(af[ii], bf[jj], acc[ii][jj], 0, 0, 0);
    }
  }

  const int col0 = tn * 128 + wn * 64, row0 = tm * 128 + wm * 64;
#pragma unroll
  for (int ii = 0; ii < 4; ++ii)
#pragma unroll
    for (int jj = 0; jj < 4; ++jj) {
      int c = col0 + jj * 16 + (lane & 15);
      int rbase = row0 + ii * 16 + (lane >> 4) * 4;
      float bv = bias ? bias[c] : 0.f;
#pragma unroll
      for (int rr = 0; rr < 4; ++rr)
        C[(size_t)(rbase + rr) * N + c] = acc[ii][jj][rr] + bv;
    }
}

// ---------------- big GEMM (projection): 256x256 8-phase ----------------
#define BAR __builtin_amdgcn_s_barrier()
#define LG0 asm volatile("s_waitcnt lgkmcnt(0)")

__global__ __launch_bounds__(512) void gemm256(
    const f16* __restrict__ A, const f16* __restrict__ Bt,
    const float* __restrict__ bias, float* __restrict__ C,
    int M, int N, int K) {
  __shared__ __align__(16) f16 sm[65536]; // 128 KiB

  const int nwg = gridDim.x, bid = blockIdx.x;
  const int cpx = nwg >> 3;
  const int ii = (bid & 7) * cpx + (bid >> 3);
  const int ntm = M >> 8;
  const int tm = ii % ntm, tn = ii / ntm;

  const int tid = threadIdx.x;
  const int lane = tid & 63, w = tid >> 6;
  const int wm = w >> 2, wn = w & 3;
  const int r = lane & 15, kb = lane >> 4;

  const int srow = tid >> 3;
  const int slot8 = ((tid & 7) ^ (srow & 7)) * 8;
  const f16* gA = A + (size_t)(tm * 256 + srow) * K + slot8;
  const f16* gB = Bt + (size_t)(tn * 256 + srow) * K + slot8;
  const int lw = w * 512; // per-wave LDS staging offset (f16)

  const int NK = K >> 6;

  f32x4 acc[8][4] = {};
  f16x8 a[4][2], b[4][2];

#define STG(kt, ab, R0)                                                        \
  do {                                                                         \
    const f16* gsrc = (ab) ? gB : gA;                                          \
    f16* lb = sm + ((kt) & 1) * 32768 + (ab) * 16384 + (R0) * 64 + lw;         \
    GLOAD16(gsrc + (size_t)(R0) * K + (kt) * 64, lb);                          \
    GLOAD16(gsrc + (size_t)((R0) + 64) * K + (kt) * 64, lb + 4096);            \
  } while (0)

#define LDA(MH)                                                                \
  _Pragma("unroll") for (int i = 0; i < 4; ++i)                                \
  _Pragma("unroll") for (int kk = 0; kk < 2; ++kk)                             \
      a[i][kk] = *(const f16x8*)(Abuf + (wm * 128 + (MH) * 64 + i * 16 + r) * 64 + \
                                 (((kk * 4 + kb) ^ (r & 7)) * 8));

#define LDB(J0)                                                                \
  _Pragma("unroll") for (int j = 0; j < 2; ++j)                                \
  _Pragma("unroll") for (int kk = 0; kk < 2; ++kk)                             \
      b[(J0) + j][kk] = *(const f16x8*)(Bbuf + (wn * 64 + ((J0) + j) * 16 + r) * 64 + \
                                        (((kk * 4 + kb) ^ (r & 7)) * 8));

#define MFMA_Q(MI0, J0)                                                        \
  __builtin_amdgcn_s_setprio(1);                                               \
  _Pragma("unroll") for (int mi = 0; mi < 4; ++mi)                             \
  _Pragma("unroll") for (int j = 0; j < 2; ++j)                                \
  _Pragma("unroll") for (int kk = 0; kk < 2; ++kk)                             \
      acc[(MI0) + mi][(J0) + j] = __builtin_amdgcn_mfma_f32_16x16x32_f16(      \
          a[mi][kk], b[(J0) + j][kk], acc[(MI0) + mi][(J0) + j], 0, 0, 0);     \
  __builtin_amdgcn_s_setprio(0);

  STG(0, 0, 0); STG(0, 0, 128);
  STG(0, 1, 0); STG(0, 1, 128);
  STG(1, 0, 0); STG(1, 0, 128);
  asm volatile("s_waitcnt vmcnt(4)");
  BAR;

  for (int k = 0; k < NK; ++k) {
    const f16* Abuf = sm + (k & 1) * 32768;
    const f16* Bbuf = Abuf + 16384;
    const int kn1 = (k + 1 == NK) ? 0 : k + 1;
    const int kn2 = (k + 2 >= NK) ? k + 2 - NK : k + 2;

    LDA(0); LDB(0);
    STG(kn1, 1, 0);
    BAR; LG0;
    MFMA_Q(0, 0);
    BAR;

    LDB(2);
    STG(kn1, 1, 128);
    BAR; LG0;
    MFMA_Q(0, 2);
    BAR;

    LDA(1);
    BAR; LG0;
    MFMA_Q(4, 2);
    BAR;

    STG(kn2, 0, 0); STG(kn2, 0, 128);
    BAR;
    MFMA_Q(4, 0);
    asm volatile("s_waitcnt vmcnt(4)");
    BAR;
  }

  // epilogue: D frag col=lane&15, row=(lane>>4)*4+reg; nontemporal (write-once)
#pragma unroll
  for (int mi = 0; mi < 8; ++mi)
#pragma unroll
    for (int j = 0; j < 4; ++j) {
      int c = tn * 256 + wn * 64 + j * 16 + r;
      int rbase = tm * 256 + wm * 128 + mi * 16 + kb * 4;
      float bv = bias[c];
#pragma unroll
      for (int q = 0; q < 4; ++q)
        __builtin_nontemporal_store(acc[mi][j][q] + bv,
                                    C + (size_t)(rbase + q) * N + c);
    }
#undef STG
#undef LDA
#undef LDB
#undef MFMA_Q
}

// ---------------- cooperative MFMA recurrence (R6 + quarter barrier) ----------------
// 64 blocks x 256 threads. Block bn owns output cols [bn*16, bn*16+16), which
// lie in K-quarter q = bn>>4. Arrival bumps cnt[q*64] (4 counters, separate
// cache lines -> parallel RMW streams). Wave w consumes k in [w*256,w*256+256)
// so it polls ONLY cnt[w*64] >= (t+1)*16: staggered release, 16-producer fan-in.
__global__ __launch_bounds__(256) void recurrence_mfma(
    const f16* __restrict__ Ht,    // H^T f16 [col][k]
    const float* __restrict__ xI,  // [T*B][Hd], includes b1
    const f16* __restrict__ h0f,   // [B][Hd] f16
    f16* __restrict__ hs,          // [T*B][Hd] f16
    float* __restrict__ hN,        // [B][Hd] f32
    int* __restrict__ cnt) {       // int[256]; counters at cnt[0,64,128,192]
  __shared__ float red[4][512];
  const int tid = threadIdx.x;
  const int lane = tid & 63, w = tid >> 6;
  const int bn = blockIdx.x;
  const int r = lane & 15, kb = lane >> 4;
  const int colg = bn * 16 + r;
  const int myq = bn >> 4; // this block's output quarter

  f16x8 bH[8];
#pragma unroll
  for (int ks = 0; ks < 8; ++ks)
    bH[ks] = *(const f16x8*)(Ht + (size_t)colg * Hd + w * 256 + ks * 32 + kb * 8);

  const int eb = tid >> 3, ecp = tid & 7;

  for (int t = 0; t < Tt; ++t) {
    const f16* hp = t ? hs + (size_t)(t - 1) * Bb * Hd : h0f;
    // hoist xI off the post-barrier critical path
    const float2 xv = *(const float2*)(xI + (size_t)(t * Bb + eb) * Hd + bn * 16 + 2 * ecp);
    f32x4 acc[2] = {};
#pragma unroll
    for (int mt = 0; mt < 2; ++mt) {
      f16x8 af[8];
#pragma unroll
      for (int ks = 0; ks < 8; ++ks)
        af[ks] = *(const f16x8*)(hp + (size_t)(mt * 16 + r) * Hd + w * 256 + ks * 32 + kb * 8);
#pragma unroll
      for (int ks = 0; ks < 8; ++ks)
        acc[mt] = __builtin_amdgcn_mfma_f32_16x16x32_f16(af[ks], bH[ks], acc[mt], 0, 0, 0);
    }
#pragma unroll
    for (int mt = 0; mt < 2; ++mt)
#pragma unroll
      for (int q = 0; q < 4; ++q)
        red[w][mt * 256 + (kb * 4 + q) * 16 + r] = acc[mt][q];
    __syncthreads();

    {
      const float2 r0 = *(const float2*)&red[0][eb * 16 + 2 * ecp];
      const float2 r1 = *(const float2*)&red[1][eb * 16 + 2 * ecp];
      const float2 r2 = *(const float2*)&red[2][eb * 16 + 2 * ecp];
      const float2 r3 = *(const float2*)&red[3][eb * 16 + 2 * ecp];
      float v0 = r0.x + r1.x + r2.x + r3.x + xv.x;
      float v1 = r0.y + r1.y + r2.y + r3.y + xv.y;
      float s0 = 1.f / (1.f + __expf(-v0));
      float s1 = 1.f / (1.f + __expf(-v1));
      union { f16 h[2]; unsigned u; } pk;
      pk.h[0] = (f16)s0;
      pk.h[1] = (f16)s1;
      unsigned* dst = (unsigned*)(hs + (size_t)(t * Bb + eb) * Hd + bn * 16 + 2 * ecp);
      __hip_atomic_store(dst, pk.u, __ATOMIC_RELAXED, __HIP_MEMORY_SCOPE_AGENT);
      if (t == Tt - 1)
        *(float2*)(hN + (size_t)eb * Hd + bn * 16 + 2 * ecp) = make_float2(s0, s1);
    }

    // ---- quarter-grained grid barrier ----
    __syncthreads(); // red reads done; vmcnt(0) drained block-wide (incl. sc1 stores)
    if (tid == 0)
      (void)__hip_atomic_fetch_add(cnt + myq * 64, 1, __ATOMIC_RELAXED, __HIP_MEMORY_SCOPE_AGENT);
    const int target = (t + 1) * 16;
    while (__hip_atomic_load(cnt + w * 64, __ATOMIC_RELAXED, __HIP_MEMORY_SCOPE_AGENT) < target)
      __builtin_amdgcn_s_sleep(1);
    asm volatile("" ::: "memory"); // no h-load hoisting above the poll
  }
}

// ---------------- launcher ----------------
extern "C" void kernel_launch(void* const* d_in, const int* in_sizes, int n_in,
                              void* d_out, int out_size, void* d_ws, size_t ws_size,
                              hipStream_t stream) {
  const int* input_x = (const int*)d_in[0];
  const float* h0 = (const float*)d_in[1];
  const float* emb = (const float*)d_in[2];
  const float* Hm = (const float*)d_in[3];
  const float* Im = (const float*)d_in[4];
  const float* b1 = (const float*)d_in[5];
  const float* Um = (const float*)d_in[6];
  const float* b2 = (const float*)d_in[7];
  float* out = (float*)d_out;

  char* ws = (char*)d_ws;
  size_t off = 0;
  auto alloc = [&](size_t bytes) { void* p = ws + off; off = (off + bytes + 255) & ~(size_t)255; return p; };
  f16* Ut = (f16*)alloc((size_t)Vv * Hd * 2);
  f16* It = (f16*)alloc((size_t)Hd * Ee * 2);
  f16* Ht = (f16*)alloc((size_t)Hd * Hd * 2);
  f16* xg = (f16*)alloc((size_t)Mm * Ee * 2);
  float* xI = (float*)alloc((size_t)Mm * Hd * 4);
  f16* hs = (f16*)alloc((size_t)Mm * Hd * 2);
  f16* h0f = (f16*)alloc((size_t)Bb * Hd * 2);
  int* cnt = (int*)alloc(1024); // 4 quarter-counters at 256B stride
  (void)ws_size; (void)in_sizes; (void)n_in; (void)out_size;

  hipMemsetAsync(cnt, 0, 1024, stream);

  transpose_cvt<<<dim3(Vv / 32, Hd / 32), dim3(32, 8), 0, stream>>>(Um, Ut, Hd, Vv);
  transpose_cvt<<<dim3(Hd / 32, Ee / 32), dim3(32, 8), 0, stream>>>(Im, It, Ee, Hd);
  transpose_cvt<<<dim3(Hd / 32, Hd / 32), dim3(32, 8), 0, stream>>>(Hm, Ht, Hd, Hd);
  gather_emb<<<Mm, 256, 0, stream>>>(input_x, emb, xg);
  cvt_h0<<<(Bb * Hd) / 256, 256, 0, stream>>>(h0, h0f);

  // xI = xg @ I + b1   (M=2048, N=1024, K=1024), grid 128 (%8==0)
  gemm_f16<<<(Mm / 128) * (Hd / 128), 256, 0, stream>>>(xg, It, b1, xI, Mm, Hd, Ee);

  // recurrence -> hs (f16) and final state -> tail of d_out
  recurrence_mfma<<<64, 256, 0, stream>>>(Ht, xI, h0f, hs, out + (size_t)Mm * Vv, cnt);

  // logits = hs @ U + b2   (M=2048, N=32000, K=1024), grid 1000 (%8==0)
  gemm256<<<(Mm / 256) * (Vv / 256), 512, 0, stream>>>(hs, Ut, b2, out, Mm, Vv, Hd);
}

// Round 9
// 494.641 us; speedup vs baseline: 1.9132x; 1.0523x over previous
//
#include <hip/hip_runtime.h>

// RNNLM: logits[T,B,V] = (scan_t sigmoid(h@H + emb[x]@I + b1)) @ U + b2 ; plus final h.
// V=32000 E=1024 Hd=1024 T=64 B=32.
// R9:
//  (1) recurrence: byte-level revert to R6 (single cnt, tid0 RMW arrival,
//      all-thread poll, xI hoist; 258us proven). Barrier experiments closed:
//      R4/R5/R8 all regressed vs this form.
//  (2) gemm256: tm-PAIR-major block order under the same XCD chunking.
//      Old order put 8 A-panels (4MB) + 4 B-panels (2MB) = 6MB in each XCD's
//      4MB L2 -> A thrashed to L3 (~16TB/s demand) -> MfmaUtil 38%. New order
//      L = tp*2*ntn + tn*2 + tm_lsb gives each XCD exactly 2 A-panels (1MB,
//      L2-resident); B streams once from HBM, reused by the adjacent pair.
//      1000 = 8 chunks of 125 aligns: XCDs {0,1}->tp0 ... {6,7}->tp3.

typedef _Float16 f16;
typedef f16 f16x4 __attribute__((ext_vector_type(4)));
typedef f16 f16x8 __attribute__((ext_vector_type(8)));
typedef float f32x4 __attribute__((ext_vector_type(4)));

static constexpr int Vv = 32000, Ee = 1024, Hd = 1024, Tt = 64, Bb = 32;
static constexpr int Mm = Tt * Bb; // 2048 rows (t*B+b)

// async global->LDS, 16B per lane; LDS dest = wave-uniform base + lane*16
#define GLOAD16(g, l)                                                          \
  __builtin_amdgcn_global_load_lds(                                            \
      (const __attribute__((address_space(1))) void*)(g),                      \
      (__attribute__((address_space(3))) void*)(l), 16, 0, 0)

// ---------------- prep kernels ----------------

__global__ void transpose_cvt(const float* __restrict__ in, f16* __restrict__ out,
                              int K, int N) {
  __shared__ float t[32][33];
  int n0 = blockIdx.x * 32, k0 = blockIdx.y * 32;
  int tx = threadIdx.x, ty = threadIdx.y; // (32,8)
#pragma unroll
  for (int i = 0; i < 32; i += 8)
    t[ty + i][tx] = in[(size_t)(k0 + ty + i) * N + n0 + tx];
  __syncthreads();
#pragma unroll
  for (int i = 0; i < 32; i += 8)
    out[(size_t)(n0 + ty + i) * K + k0 + tx] = (f16)t[tx][ty + i];
}

__global__ void gather_emb(const int* __restrict__ tok, const float* __restrict__ emb,
                           f16* __restrict__ xg) {
  int m = blockIdx.x;
  int b = m % Bb, t = m / Bb;
  int token = tok[b * Tt + t];
  const float* src = emb + (size_t)token * Ee;
  f16* dst = xg + (size_t)m * Ee;
  int e = threadIdx.x * 4;
  float4 v = *(const float4*)(src + e);
  f16x4 o = {(f16)v.x, (f16)v.y, (f16)v.z, (f16)v.w};
  *(f16x4*)(dst + e) = o;
}

__global__ void cvt_h0(const float* __restrict__ h0, f16* __restrict__ h0f) {
  int i = blockIdx.x * 256 + threadIdx.x;
  h0f[i] = (f16)h0[i];
}

// ---------------- small GEMM (xI): 128x128 tile, BK=64, proven R4 ----------------
__global__ __launch_bounds__(256) void gemm_f16(
    const f16* __restrict__ A, const f16* __restrict__ Bt,
    const float* __restrict__ bias, float* __restrict__ C, int M, int N, int K) {
  __shared__ __align__(16) f16 As[128 * 64];
  __shared__ __align__(16) f16 Bs[128 * 64];

  const int nwg = gridDim.x, bid = blockIdx.x;
  const int cpx = nwg >> 3;
  const int i = (bid & 7) * cpx + (bid >> 3);
  const int ntm = M >> 7;
  const int tm = i % ntm, tn = i / ntm;

  const int tid = threadIdx.x;
  const int lane = tid & 63, wid = tid >> 6;
  const int wm = wid >> 1, wn = wid & 1;

  const int srow = lane >> 3;
  const int sslot = (lane & 7) ^ srow;
  const f16* gA = A + (size_t)(tm * 128 + wid * 8 + srow) * K + sslot * 8;
  const f16* gB = Bt + (size_t)(tn * 128 + wid * 8 + srow) * K + sslot * 8;
  f16* lA = As + wid * 8 * 64;
  f16* lB = Bs + wid * 8 * 64;

  f32x4 acc[4][4] = {};
  const int r = lane & 15, kb = lane >> 4;

  for (int kc = 0; kc < K; kc += 64) {
    __syncthreads();
#pragma unroll
    for (int rr = 0; rr < 4; ++rr) {
      GLOAD16(gA + (size_t)rr * 32 * K + kc, lA + rr * 2048);
      GLOAD16(gB + (size_t)rr * 32 * K + kc, lB + rr * 2048);
    }
    __syncthreads();

#pragma unroll
    for (int kk = 0; kk < 2; ++kk) {
      f16x8 af[4], bf[4];
#pragma unroll
      for (int ii = 0; ii < 4; ++ii) {
        const int rowA = wm * 64 + ii * 16 + r;
        const int rowB = wn * 64 + ii * 16 + r;
        const int slot = ((kk * 4 + kb) ^ (r & 7)) * 8;
        af[ii] = *(const f16x8*)(As + rowA * 64 + slot);
        bf[ii] = *(const f16x8*)(Bs + rowB * 64 + slot);
      }
#pragma unroll
      for (int ii = 0; ii < 4; ++ii)
#pragma unroll
        for (int jj = 0; jj < 4; ++jj)
          acc[ii][jj] = __builtin_amdgcn_mfma_f32_16x16x32_f16(af[ii], bf[jj], acc[ii][jj], 0, 0, 0);
    }
  }

  const int col0 = tn * 128 + wn * 64, row0 = tm * 128 + wm * 64;
#pragma unroll
  for (int ii = 0; ii < 4; ++ii)
#pragma unroll
    for (int jj = 0; jj < 4; ++jj) {
      int c = col0 + jj * 16 + (lane & 15);
      int rbase = row0 + ii * 16 + (lane >> 4) * 4;
      float bv = bias ? bias[c] : 0.f;
#pragma unroll
      for (int rr = 0; rr < 4; ++rr)
        C[(size_t)(rbase + rr) * N + c] = acc[ii][jj][rr] + bv;
    }
}

// ---------------- big GEMM (projection): 256x256 8-phase ----------------
#define BAR __builtin_amdgcn_s_barrier()
#define LG0 asm volatile("s_waitcnt lgkmcnt(0)")

__global__ __launch_bounds__(512) void gemm256(
    const f16* __restrict__ A, const f16* __restrict__ Bt,
    const float* __restrict__ bias, float* __restrict__ C,
    int M, int N, int K) {
  __shared__ __align__(16) f16 sm[65536]; // 128 KiB

  // XCD chunking + tm-PAIR-major order: each XCD's 125 consecutive ids hold
  // one tm-pair (2 A-panels = 1MB L2-resident); tn advances every 2 ids so the
  // pair shares each streamed B-panel.
  const int nwg = gridDim.x, bid = blockIdx.x;
  const int cpx = nwg >> 3;
  const int ii = (bid & 7) * cpx + (bid >> 3);
  const int ntn = N >> 8;
  const int tp = ii / (2 * ntn);
  const int rem = ii % (2 * ntn);
  const int tn = rem >> 1;
  const int tm = tp * 2 + (rem & 1);

  const int tid = threadIdx.x;
  const int lane = tid & 63, w = tid >> 6;
  const int wm = w >> 2, wn = w & 3;
  const int r = lane & 15, kb = lane >> 4;

  const int srow = tid >> 3;
  const int slot8 = ((tid & 7) ^ (srow & 7)) * 8;
  const f16* gA = A + (size_t)(tm * 256 + srow) * K + slot8;
  const f16* gB = Bt + (size_t)(tn * 256 + srow) * K + slot8;
  const int lw = w * 512; // per-wave LDS staging offset (f16)

  const int NK = K >> 6;

  f32x4 acc[8][4] = {};
  f16x8 a[4][2], b[4][2];

#define STG(kt, ab, R0)                                                        \
  do {                                                                         \
    const f16* gsrc = (ab) ? gB : gA;                                          \
    f16* lb = sm + ((kt) & 1) * 32768 + (ab) * 16384 + (R0) * 64 + lw;         \
    GLOAD16(gsrc + (size_t)(R0) * K + (kt) * 64, lb);                          \
    GLOAD16(gsrc + (size_t)((R0) + 64) * K + (kt) * 64, lb + 4096);            \
  } while (0)

#define LDA(MH)                                                                \
  _Pragma("unroll") for (int i = 0; i < 4; ++i)                                \
  _Pragma("unroll") for (int kk = 0; kk < 2; ++kk)                             \
      a[i][kk] = *(const f16x8*)(Abuf + (wm * 128 + (MH) * 64 + i * 16 + r) * 64 + \
                                 (((kk * 4 + kb) ^ (r & 7)) * 8));

#define LDB(J0)                                                                \
  _Pragma("unroll") for (int j = 0; j < 2; ++j)                                \
  _Pragma("unroll") for (int kk = 0; kk < 2; ++kk)                             \
      b[(J0) + j][kk] = *(const f16x8*)(Bbuf + (wn * 64 + ((J0) + j) * 16 + r) * 64 + \
                                        (((kk * 4 + kb) ^ (r & 7)) * 8));

#define MFMA_Q(MI0, J0)                                                        \
  __builtin_amdgcn_s_setprio(1);                                               \
  _Pragma("unroll") for (int mi = 0; mi < 4; ++mi)                             \
  _Pragma("unroll") for (int j = 0; j < 2; ++j)                                \
  _Pragma("unroll") for (int kk = 0; kk < 2; ++kk)                             \
      acc[(MI0) + mi][(J0) + j] = __builtin_amdgcn_mfma_f32_16x16x32_f16(      \
          a[mi][kk], b[(J0) + j][kk], acc[(MI0) + mi][(J0) + j], 0, 0, 0);     \
  __builtin_amdgcn_s_setprio(0);

  STG(0, 0, 0); STG(0, 0, 128);
  STG(0, 1, 0); STG(0, 1, 128);
  STG(1, 0, 0); STG(1, 0, 128);
  asm volatile("s_waitcnt vmcnt(4)");
  BAR;

  for (int k = 0; k < NK; ++k) {
    const f16* Abuf = sm + (k & 1) * 32768;
    const f16* Bbuf = Abuf + 16384;
    const int kn1 = (k + 1 == NK) ? 0 : k + 1;
    const int kn2 = (k + 2 >= NK) ? k + 2 - NK : k + 2;

    LDA(0); LDB(0);
    STG(kn1, 1, 0);
    BAR; LG0;
    MFMA_Q(0, 0);
    BAR;

    LDB(2);
    STG(kn1, 1, 128);
    BAR; LG0;
    MFMA_Q(0, 2);
    BAR;

    LDA(1);
    BAR; LG0;
    MFMA_Q(4, 2);
    BAR;

    STG(kn2, 0, 0); STG(kn2, 0, 128);
    BAR;
    MFMA_Q(4, 0);
    asm volatile("s_waitcnt vmcnt(4)");
    BAR;
  }

  // epilogue: D frag col=lane&15, row=(lane>>4)*4+reg; nontemporal (write-once)
#pragma unroll
  for (int mi = 0; mi < 8; ++mi)
#pragma unroll
    for (int j = 0; j < 4; ++j) {
      int c = tn * 256 + wn * 64 + j * 16 + r;
      int rbase = tm * 256 + wm * 128 + mi * 16 + kb * 4;
      float bv = bias[c];
#pragma unroll
      for (int q = 0; q < 4; ++q)
        __builtin_nontemporal_store(acc[mi][j][q] + bv,
                                    C + (size_t)(rbase + q) * N + c);
    }
#undef STG
#undef LDA
#undef LDB
#undef MFMA_Q
}

// ---------------- cooperative MFMA recurrence (R6-proven, 258us) ----------------
__global__ __launch_bounds__(256) void recurrence_mfma(
    const f16* __restrict__ Ht,    // H^T f16 [col][k]
    const float* __restrict__ xI,  // [T*B][Hd], includes b1
    const f16* __restrict__ h0f,   // [B][Hd] f16
    f16* __restrict__ hs,          // [T*B][Hd] f16
    float* __restrict__ hN,        // [B][Hd] f32
    int* __restrict__ cnt) {
  __shared__ float red[4][512];
  const int tid = threadIdx.x;
  const int lane = tid & 63, w = tid >> 6;
  const int bn = blockIdx.x;
  const int nb = gridDim.x;
  const int r = lane & 15, kb = lane >> 4;
  const int colg = bn * 16 + r;

  f16x8 bH[8];
#pragma unroll
  for (int ks = 0; ks < 8; ++ks)
    bH[ks] = *(const f16x8*)(Ht + (size_t)colg * Hd + w * 256 + ks * 32 + kb * 8);

  const int eb = tid >> 3, ecp = tid & 7;

  for (int t = 0; t < Tt; ++t) {
    const f16* hp = t ? hs + (size_t)(t - 1) * Bb * Hd : h0f;
    // hoist xI off the post-barrier critical path
    const float2 xv = *(const float2*)(xI + (size_t)(t * Bb + eb) * Hd + bn * 16 + 2 * ecp);
    f32x4 acc[2] = {};
#pragma unroll
    for (int mt = 0; mt < 2; ++mt) {
      f16x8 af[8];
#pragma unroll
      for (int ks = 0; ks < 8; ++ks)
        af[ks] = *(const f16x8*)(hp + (size_t)(mt * 16 + r) * Hd + w * 256 + ks * 32 + kb * 8);
#pragma unroll
      for (int ks = 0; ks < 8; ++ks)
        acc[mt] = __builtin_amdgcn_mfma_f32_16x16x32_f16(af[ks], bH[ks], acc[mt], 0, 0, 0);
    }
#pragma unroll
    for (int mt = 0; mt < 2; ++mt)
#pragma unroll
      for (int q = 0; q < 4; ++q)
        red[w][mt * 256 + (kb * 4 + q) * 16 + r] = acc[mt][q];
    __syncthreads();

    {
      const float2 r0 = *(const float2*)&red[0][eb * 16 + 2 * ecp];
      const float2 r1 = *(const float2*)&red[1][eb * 16 + 2 * ecp];
      const float2 r2 = *(const float2*)&red[2][eb * 16 + 2 * ecp];
      const float2 r3 = *(const float2*)&red[3][eb * 16 + 2 * ecp];
      float v0 = r0.x + r1.x + r2.x + r3.x + xv.x;
      float v1 = r0.y + r1.y + r2.y + r3.y + xv.y;
      float s0 = 1.f / (1.f + __expf(-v0));
      float s1 = 1.f / (1.f + __expf(-v1));
      union { f16 h[2]; unsigned u; } pk;
      pk.h[0] = (f16)s0;
      pk.h[1] = (f16)s1;
      unsigned* dst = (unsigned*)(hs + (size_t)(t * Bb + eb) * Hd + bn * 16 + 2 * ecp);
      __hip_atomic_store(dst, pk.u, __ATOMIC_RELAXED, __HIP_MEMORY_SCOPE_AGENT);
      if (t == Tt - 1)
        *(float2*)(hN + (size_t)eb * Hd + bn * 16 + 2 * ecp) = make_float2(s0, s1);
    }

    // ---- grid barrier (R3/R6-proven): drain -> tid0 RMW -> all-thread poll ----
    __syncthreads(); // red reads done; vmcnt(0) drained block-wide (incl. sc1 stores)
    if (tid == 0)
      (void)__hip_atomic_fetch_add(cnt, 1, __ATOMIC_RELAXED, __HIP_MEMORY_SCOPE_AGENT);
    const int target = (t + 1) * nb;
    while (__hip_atomic_load(cnt, __ATOMIC_RELAXED, __HIP_MEMORY_SCOPE_AGENT) < target)
      __builtin_amdgcn_s_sleep(1);
    asm volatile("" ::: "memory"); // no h-load hoisting above the poll
  }
}

// ---------------- launcher ----------------
extern "C" void kernel_launch(void* const* d_in, const int* in_sizes, int n_in,
                              void* d_out, int out_size, void* d_ws, size_t ws_size,
                              hipStream_t stream) {
  const int* input_x = (const int*)d_in[0];
  const float* h0 = (const float*)d_in[1];
  const float* emb = (const float*)d_in[2];
  const float* Hm = (const float*)d_in[3];
  const float* Im = (const float*)d_in[4];
  const float* b1 = (const float*)d_in[5];
  const float* Um = (const float*)d_in[6];
  const float* b2 = (const float*)d_in[7];
  float* out = (float*)d_out;

  char* ws = (char*)d_ws;
  size_t off = 0;
  auto alloc = [&](size_t bytes) { void* p = ws + off; off = (off + bytes + 255) & ~(size_t)255; return p; };
  f16* Ut = (f16*)alloc((size_t)Vv * Hd * 2);
  f16* It = (f16*)alloc((size_t)Hd * Ee * 2);
  f16* Ht = (f16*)alloc((size_t)Hd * Hd * 2);
  f16* xg = (f16*)alloc((size_t)Mm * Ee * 2);
  float* xI = (float*)alloc((size_t)Mm * Hd * 4);
  f16* hs = (f16*)alloc((size_t)Mm * Hd * 2);
  f16* h0f = (f16*)alloc((size_t)Bb * Hd * 2);
  int* cnt = (int*)alloc(256);
  (void)ws_size; (void)in_sizes; (void)n_in; (void)out_size;

  hipMemsetAsync(cnt, 0, sizeof(int), stream);

  transpose_cvt<<<dim3(Vv / 32, Hd / 32), dim3(32, 8), 0, stream>>>(Um, Ut, Hd, Vv);
  transpose_cvt<<<dim3(Hd / 32, Ee / 32), dim3(32, 8), 0, stream>>>(Im, It, Ee, Hd);
  transpose_cvt<<<dim3(Hd / 32, Hd / 32), dim3(32, 8), 0, stream>>>(Hm, Ht, Hd, Hd);
  gather_emb<<<Mm, 256, 0, stream>>>(input_x, emb, xg);
  cvt_h0<<<(Bb * Hd) / 256, 256, 0, stream>>>(h0, h0f);

  // xI = xg @ I + b1   (M=2048, N=1024, K=1024), grid 128 (%8==0)
  gemm_f16<<<(Mm / 128) * (Hd / 128), 256, 0, stream>>>(xg, It, b1, xI, Mm, Hd, Ee);

  // recurrence -> hs (f16) and final state -> tail of d_out
  recurrence_mfma<<<64, 256, 0, stream>>>(Ht, xI, h0f, hs, out + (size_t)Mm * Vv, cnt);

  // logits = hs @ U + b2   (M=2048, N=32000, K=1024), grid 1000 (%8==0)
  gemm256<<<(Mm / 256) * (Vv / 256), 512, 0, stream>>>(hs, Ut, b2, out, Mm, Vv, Hd);
}

// Round 10
// 467.164 us; speedup vs baseline: 2.0257x; 1.0588x over previous
//
#include <hip/hip_runtime.h>

// RNNLM: logits[T,B,V] = (scan_t sigmoid(h@H + emb[x]@I + b1)) @ U + b2 ; plus final h.
// V=32000 E=1024 Hd=1024 T=64 B=32.
// R10:
//  (1) combo kernel: recurrence (blocks 0..63, R6-proven bytes, nb hardcoded)
//      + Ut transpose on blocks 64..255 (grid-stride 32x32 tiles). The 196MB
//      transpose (35us serial) now runs on the 192 CUs the recurrence leaves
//      idle; no inter-role sync (Ut consumed only by gemm256, stream-ordered).
//      256 blocks <= 256 CUs -> co-resident; transpose blocks retire early.
//  (2) gemm256: ordering reverted to R6 tm-fastest (R9 pair-major measured
//      neutral; keep the simpler proven form). Staging-traffic analysis says
//      gemm256 is tile-BW bound (1GB staged vs 271MB unique) - bigger levers
//      (fp8 B) deferred.

typedef _Float16 f16;
typedef f16 f16x4 __attribute__((ext_vector_type(4)));
typedef f16 f16x8 __attribute__((ext_vector_type(8)));
typedef float f32x4 __attribute__((ext_vector_type(4)));

static constexpr int Vv = 32000, Ee = 1024, Hd = 1024, Tt = 64, Bb = 32;
static constexpr int Mm = Tt * Bb; // 2048 rows (t*B+b)
static constexpr int NBR = 64;     // recurrence blocks in combo
static constexpr int NBT = 192;    // transpose blocks in combo

// async global->LDS, 16B per lane; LDS dest = wave-uniform base + lane*16
#define GLOAD16(g, l)                                                          \
  __builtin_amdgcn_global_load_lds(                                            \
      (const __attribute__((address_space(1))) void*)(g),                      \
      (__attribute__((address_space(3))) void*)(l), 16, 0, 0)

// ---------------- prep kernels ----------------

__global__ void transpose_cvt(const float* __restrict__ in, f16* __restrict__ out,
                              int K, int N) {
  __shared__ float t[32][33];
  int n0 = blockIdx.x * 32, k0 = blockIdx.y * 32;
  int tx = threadIdx.x, ty = threadIdx.y; // (32,8)
#pragma unroll
  for (int i = 0; i < 32; i += 8)
    t[ty + i][tx] = in[(size_t)(k0 + ty + i) * N + n0 + tx];
  __syncthreads();
#pragma unroll
  for (int i = 0; i < 32; i += 8)
    out[(size_t)(n0 + ty + i) * K + k0 + tx] = (f16)t[tx][ty + i];
}

__global__ void gather_emb(const int* __restrict__ tok, const float* __restrict__ emb,
                           f16* __restrict__ xg) {
  int m = blockIdx.x;
  int b = m % Bb, t = m / Bb;
  int token = tok[b * Tt + t];
  const float* src = emb + (size_t)token * Ee;
  f16* dst = xg + (size_t)m * Ee;
  int e = threadIdx.x * 4;
  float4 v = *(const float4*)(src + e);
  f16x4 o = {(f16)v.x, (f16)v.y, (f16)v.z, (f16)v.w};
  *(f16x4*)(dst + e) = o;
}

__global__ void cvt_h0(const float* __restrict__ h0, f16* __restrict__ h0f) {
  int i = blockIdx.x * 256 + threadIdx.x;
  h0f[i] = (f16)h0[i];
}

// ---------------- small GEMM (xI): 128x128 tile, BK=64, proven R4 ----------------
__global__ __launch_bounds__(256) void gemm_f16(
    const f16* __restrict__ A, const f16* __restrict__ Bt,
    const float* __restrict__ bias, float* __restrict__ C, int M, int N, int K) {
  __shared__ __align__(16) f16 As[128 * 64];
  __shared__ __align__(16) f16 Bs[128 * 64];

  const int nwg = gridDim.x, bid = blockIdx.x;
  const int cpx = nwg >> 3;
  const int i = (bid & 7) * cpx + (bid >> 3);
  const int ntm = M >> 7;
  const int tm = i % ntm, tn = i / ntm;

  const int tid = threadIdx.x;
  const int lane = tid & 63, wid = tid >> 6;
  const int wm = wid >> 1, wn = wid & 1;

  const int srow = lane >> 3;
  const int sslot = (lane & 7) ^ srow;
  const f16* gA = A + (size_t)(tm * 128 + wid * 8 + srow) * K + sslot * 8;
  const f16* gB = Bt + (size_t)(tn * 128 + wid * 8 + srow) * K + sslot * 8;
  f16* lA = As + wid * 8 * 64;
  f16* lB = Bs + wid * 8 * 64;

  f32x4 acc[4][4] = {};
  const int r = lane & 15, kb = lane >> 4;

  for (int kc = 0; kc < K; kc += 64) {
    __syncthreads();
#pragma unroll
    for (int rr = 0; rr < 4; ++rr) {
      GLOAD16(gA + (size_t)rr * 32 * K + kc, lA + rr * 2048);
      GLOAD16(gB + (size_t)rr * 32 * K + kc, lB + rr * 2048);
    }
    __syncthreads();

#pragma unroll
    for (int kk = 0; kk < 2; ++kk) {
      f16x8 af[4], bf[4];
#pragma unroll
      for (int ii = 0; ii < 4; ++ii) {
        const int rowA = wm * 64 + ii * 16 + r;
        const int rowB = wn * 64 + ii * 16 + r;
        const int slot = ((kk * 4 + kb) ^ (r & 7)) * 8;
        af[ii] = *(const f16x8*)(As + rowA * 64 + slot);
        bf[ii] = *(const f16x8*)(Bs + rowB * 64 + slot);
      }
#pragma unroll
      for (int ii = 0; ii < 4; ++ii)
#pragma unroll
        for (int jj = 0; jj < 4; ++jj)
          acc[ii][jj] = __builtin_amdgcn_mfma_f32_16x16x32_f16(af[ii], bf[jj], acc[ii][jj], 0, 0, 0);
    }
  }

  const int col0 = tn * 128 + wn * 64, row0 = tm * 128 + wm * 64;
#pragma unroll
  for (int ii = 0; ii < 4; ++ii)
#pragma unroll
    for (int jj = 0; jj < 4; ++jj) {
      int c = col0 + jj * 16 + (lane & 15);
      int rbase = row0 + ii * 16 + (lane >> 4) * 4;
      float bv = bias ? bias[c] : 0.f;
#pragma unroll
      for (int rr = 0; rr < 4; ++rr)
        C[(size_t)(rbase + rr) * N + c] = acc[ii][jj][rr] + bv;
    }
}

// ---------------- big GEMM (projection): 256x256 8-phase ----------------
#define BAR __builtin_amdgcn_s_barrier()
#define LG0 asm volatile("s_waitcnt lgkmcnt(0)")

__global__ __launch_bounds__(512) void gemm256(
    const f16* __restrict__ A, const f16* __restrict__ Bt,
    const float* __restrict__ bias, float* __restrict__ C,
    int M, int N, int K) {
  __shared__ __align__(16) f16 sm[65536]; // 128 KiB

  // XCD-bijective chunking, tm-fastest (R6 proven form)
  const int nwg = gridDim.x, bid = blockIdx.x;
  const int cpx = nwg >> 3;
  const int ii = (bid & 7) * cpx + (bid >> 3);
  const int ntm = M >> 8;
  const int tm = ii % ntm, tn = ii / ntm;

  const int tid = threadIdx.x;
  const int lane = tid & 63, w = tid >> 6;
  const int wm = w >> 2, wn = w & 3;
  const int r = lane & 15, kb = lane >> 4;

  const int srow = tid >> 3;
  const int slot8 = ((tid & 7) ^ (srow & 7)) * 8;
  const f16* gA = A + (size_t)(tm * 256 + srow) * K + slot8;
  const f16* gB = Bt + (size_t)(tn * 256 + srow) * K + slot8;
  const int lw = w * 512; // per-wave LDS staging offset (f16)

  const int NK = K >> 6;

  f32x4 acc[8][4] = {};
  f16x8 a[4][2], b[4][2];

#define STG(kt, ab, R0)                                                        \
  do {                                                                         \
    const f16* gsrc = (ab) ? gB : gA;                                          \
    f16* lb = sm + ((kt) & 1) * 32768 + (ab) * 16384 + (R0) * 64 + lw;         \
    GLOAD16(gsrc + (size_t)(R0) * K + (kt) * 64, lb);                          \
    GLOAD16(gsrc + (size_t)((R0) + 64) * K + (kt) * 64, lb + 4096);            \
  } while (0)

#define LDA(MH)                                                                \
  _Pragma("unroll") for (int i = 0; i < 4; ++i)                                \
  _Pragma("unroll") for (int kk = 0; kk < 2; ++kk)                             \
      a[i][kk] = *(const f16x8*)(Abuf + (wm * 128 + (MH) * 64 + i * 16 + r) * 64 + \
                                 (((kk * 4 + kb) ^ (r & 7)) * 8));

#define LDB(J0)                                                                \
  _Pragma("unroll") for (int j = 0; j < 2; ++j)                                \
  _Pragma("unroll") for (int kk = 0; kk < 2; ++kk)                             \
      b[(J0) + j][kk] = *(const f16x8*)(Bbuf + (wn * 64 + ((J0) + j) * 16 + r) * 64 + \
                                        (((kk * 4 + kb) ^ (r & 7)) * 8));

#define MFMA_Q(MI0, J0)                                                        \
  __builtin_amdgcn_s_setprio(1);                                               \
  _Pragma("unroll") for (int mi = 0; mi < 4; ++mi)                             \
  _Pragma("unroll") for (int j = 0; j < 2; ++j)                                \
  _Pragma("unroll") for (int kk = 0; kk < 2; ++kk)                             \
      acc[(MI0) + mi][(J0) + j] = __builtin_amdgcn_mfma_f32_16x16x32_f16(      \
          a[mi][kk], b[(J0) + j][kk], acc[(MI0) + mi][(J0) + j], 0, 0, 0);     \
  __builtin_amdgcn_s_setprio(0);

  STG(0, 0, 0); STG(0, 0, 128);
  STG(0, 1, 0); STG(0, 1, 128);
  STG(1, 0, 0); STG(1, 0, 128);
  asm volatile("s_waitcnt vmcnt(4)");
  BAR;

  for (int k = 0; k < NK; ++k) {
    const f16* Abuf = sm + (k & 1) * 32768;
    const f16* Bbuf = Abuf + 16384;
    const int kn1 = (k + 1 == NK) ? 0 : k + 1;
    const int kn2 = (k + 2 >= NK) ? k + 2 - NK : k + 2;

    LDA(0); LDB(0);
    STG(kn1, 1, 0);
    BAR; LG0;
    MFMA_Q(0, 0);
    BAR;

    LDB(2);
    STG(kn1, 1, 128);
    BAR; LG0;
    MFMA_Q(0, 2);
    BAR;

    LDA(1);
    BAR; LG0;
    MFMA_Q(4, 2);
    BAR;

    STG(kn2, 0, 0); STG(kn2, 0, 128);
    BAR;
    MFMA_Q(4, 0);
    asm volatile("s_waitcnt vmcnt(4)");
    BAR;
  }

  // epilogue: D frag col=lane&15, row=(lane>>4)*4+reg; nontemporal (write-once)
#pragma unroll
  for (int mi = 0; mi < 8; ++mi)
#pragma unroll
    for (int j = 0; j < 4; ++j) {
      int c = tn * 256 + wn * 64 + j * 16 + r;
      int rbase = tm * 256 + wm * 128 + mi * 16 + kb * 4;
      float bv = bias[c];
#pragma unroll
      for (int q = 0; q < 4; ++q)
        __builtin_nontemporal_store(acc[mi][j][q] + bv,
                                    C + (size_t)(rbase + q) * N + c);
    }
#undef STG
#undef LDA
#undef LDB
#undef MFMA_Q
}

// ---------------- combo: recurrence (blocks 0..63) + Ut transpose (64..255) ----------------
__global__ __launch_bounds__(256) void rec_plus_transpose(
    const f16* __restrict__ Ht,    // H^T f16 [col][k]
    const float* __restrict__ xI,  // [T*B][Hd], includes b1
    const f16* __restrict__ h0f,   // [B][Hd] f16
    f16* __restrict__ hs,          // [T*B][Hd] f16
    float* __restrict__ hN,        // [B][Hd] f32
    int* __restrict__ cnt,
    const float* __restrict__ Um,  // U f32 [Hd][Vv]
    f16* __restrict__ Ut) {        // U^T f16 [Vv][Hd]
  __shared__ float red[4][512];    // recurrence reduce
  __shared__ float tt[32][33];     // transpose tile
  const int tid = threadIdx.x;

  if (blockIdx.x >= NBR) {
    // ---- transpose role: Ut[n][k] = (f16) U[k][n], 32x32 tiles, grid-stride ----
    const int tb = blockIdx.x - NBR;           // 0..NBT-1
    const int tx = tid & 31, ty = tid >> 5;    // 32 x 8
    const int ntile_n = Vv / 32;               // 1000
    const int ntiles = ntile_n * (Hd / 32);    // 32000
    for (int tile = tb; tile < ntiles; tile += NBT) {
      const int n0 = (tile % ntile_n) * 32, k0 = (tile / ntile_n) * 32;
#pragma unroll
      for (int i = 0; i < 32; i += 8)
        tt[ty + i][tx] = Um[(size_t)(k0 + ty + i) * Vv + n0 + tx];
      __syncthreads();
#pragma unroll
      for (int i = 0; i < 32; i += 8)
        Ut[(size_t)(n0 + ty + i) * Hd + k0 + tx] = (f16)tt[tx][ty + i];
      __syncthreads();
    }
    return;
  }

  // ---- recurrence role (R6-proven bytes; nb hardcoded to NBR) ----
  const int lane = tid & 63, w = tid >> 6;
  const int bn = blockIdx.x;
  const int r = lane & 15, kb = lane >> 4;
  const int colg = bn * 16 + r;

  f16x8 bH[8];
#pragma unroll
  for (int ks = 0; ks < 8; ++ks)
    bH[ks] = *(const f16x8*)(Ht + (size_t)colg * Hd + w * 256 + ks * 32 + kb * 8);

  const int eb = tid >> 3, ecp = tid & 7;

  for (int t = 0; t < Tt; ++t) {
    const f16* hp = t ? hs + (size_t)(t - 1) * Bb * Hd : h0f;
    // hoist xI off the post-barrier critical path
    const float2 xv = *(const float2*)(xI + (size_t)(t * Bb + eb) * Hd + bn * 16 + 2 * ecp);
    f32x4 acc[2] = {};
#pragma unroll
    for (int mt = 0; mt < 2; ++mt) {
      f16x8 af[8];
#pragma unroll
      for (int ks = 0; ks < 8; ++ks)
        af[ks] = *(const f16x8*)(hp + (size_t)(mt * 16 + r) * Hd + w * 256 + ks * 32 + kb * 8);
#pragma unroll
      for (int ks = 0; ks < 8; ++ks)
        acc[mt] = __builtin_amdgcn_mfma_f32_16x16x32_f16(af[ks], bH[ks], acc[mt], 0, 0, 0);
    }
#pragma unroll
    for (int mt = 0; mt < 2; ++mt)
#pragma unroll
      for (int q = 0; q < 4; ++q)
        red[w][mt * 256 + (kb * 4 + q) * 16 + r] = acc[mt][q];
    __syncthreads();

    {
      const float2 r0 = *(const float2*)&red[0][eb * 16 + 2 * ecp];
      const float2 r1 = *(const float2*)&red[1][eb * 16 + 2 * ecp];
      const float2 r2 = *(const float2*)&red[2][eb * 16 + 2 * ecp];
      const float2 r3 = *(const float2*)&red[3][eb * 16 + 2 * ecp];
      float v0 = r0.x + r1.x + r2.x + r3.x + xv.x;
      float v1 = r0.y + r1.y + r2.y + r3.y + xv.y;
      float s0 = 1.f / (1.f + __expf(-v0));
      float s1 = 1.f / (1.f + __expf(-v1));
      union { f16 h[2]; unsigned u; } pk;
      pk.h[0] = (f16)s0;
      pk.h[1] = (f16)s1;
      unsigned* dst = (unsigned*)(hs + (size_t)(t * Bb + eb) * Hd + bn * 16 + 2 * ecp);
      __hip_atomic_store(dst, pk.u, __ATOMIC_RELAXED, __HIP_MEMORY_SCOPE_AGENT);
      if (t == Tt - 1)
        *(float2*)(hN + (size_t)eb * Hd + bn * 16 + 2 * ecp) = make_float2(s0, s1);
    }

    // ---- grid barrier (R3/R6-proven): drain -> tid0 RMW -> all-thread poll ----
    __syncthreads(); // red reads done; vmcnt(0) drained block-wide (incl. sc1 stores)
    if (tid == 0)
      (void)__hip_atomic_fetch_add(cnt, 1, __ATOMIC_RELAXED, __HIP_MEMORY_SCOPE_AGENT);
    const int target = (t + 1) * NBR;
    while (__hip_atomic_load(cnt, __ATOMIC_RELAXED, __HIP_MEMORY_SCOPE_AGENT) < target)
      __builtin_amdgcn_s_sleep(1);
    asm volatile("" ::: "memory"); // no h-load hoisting above the poll
  }
}

// ---------------- launcher ----------------
extern "C" void kernel_launch(void* const* d_in, const int* in_sizes, int n_in,
                              void* d_out, int out_size, void* d_ws, size_t ws_size,
                              hipStream_t stream) {
  const int* input_x = (const int*)d_in[0];
  const float* h0 = (const float*)d_in[1];
  const float* emb = (const float*)d_in[2];
  const float* Hm = (const float*)d_in[3];
  const float* Im = (const float*)d_in[4];
  const float* b1 = (const float*)d_in[5];
  const float* Um = (const float*)d_in[6];
  const float* b2 = (const float*)d_in[7];
  float* out = (float*)d_out;

  char* ws = (char*)d_ws;
  size_t off = 0;
  auto alloc = [&](size_t bytes) { void* p = ws + off; off = (off + bytes + 255) & ~(size_t)255; return p; };
  f16* Ut = (f16*)alloc((size_t)Vv * Hd * 2);
  f16* It = (f16*)alloc((size_t)Hd * Ee * 2);
  f16* Ht = (f16*)alloc((size_t)Hd * Hd * 2);
  f16* xg = (f16*)alloc((size_t)Mm * Ee * 2);
  float* xI = (float*)alloc((size_t)Mm * Hd * 4);
  f16* hs = (f16*)alloc((size_t)Mm * Hd * 2);
  f16* h0f = (f16*)alloc((size_t)Bb * Hd * 2);
  int* cnt = (int*)alloc(256);
  (void)ws_size; (void)in_sizes; (void)n_in; (void)out_size;

  hipMemsetAsync(cnt, 0, sizeof(int), stream);

  // small preps (feed xI gemm / recurrence)
  transpose_cvt<<<dim3(Hd / 32, Ee / 32), dim3(32, 8), 0, stream>>>(Im, It, Ee, Hd);
  transpose_cvt<<<dim3(Hd / 32, Hd / 32), dim3(32, 8), 0, stream>>>(Hm, Ht, Hd, Hd);
  gather_emb<<<Mm, 256, 0, stream>>>(input_x, emb, xg);
  cvt_h0<<<(Bb * Hd) / 256, 256, 0, stream>>>(h0, h0f);

  // xI = xg @ I + b1   (M=2048, N=1024, K=1024), grid 128 (%8==0)
  gemm_f16<<<(Mm / 128) * (Hd / 128), 256, 0, stream>>>(xg, It, b1, xI, Mm, Hd, Ee);

  // combo: recurrence -> hs + final h; Ut transpose on the idle 192 CUs
  rec_plus_transpose<<<NBR + NBT, 256, 0, stream>>>(
      Ht, xI, h0f, hs, out + (size_t)Mm * Vv, cnt, Um, Ut);

  // logits = hs @ U + b2   (M=2048, N=32000, K=1024), grid 1000 (%8==0)
  gemm256<<<(Mm / 256) * (Vv / 256), 512, 0, stream>>>(hs, Ut, b2, out, Mm, Vv, Hd);
}